// Round 4
// baseline (1032.664 us; speedup 1.0000x reference)
//
#include <hip/hip_runtime.h>
#include <hip/hip_bf16.h>

#define NN 50000
#define NE 600000
#define DIM 128
#define NEG 0.2f
#define GEPS 1e-16f

__device__ __forceinline__ float leaky(float x) { return x > 0.f ? x : NEG * x; }

// ---------------- CSR build ----------------
__global__ __launch_bounds__(256) void k_count(const int* __restrict__ d1,
                                               const int* __restrict__ d2,
                                               int* __restrict__ cnt, int netot) {
  int e = blockIdx.x * blockDim.x + threadIdx.x;
  if (e >= netot) return;
  int dst = (e < NE) ? d1[e] : d2[e - NE] + NN;
  atomicAdd(&cnt[dst], 1);
}

__global__ __launch_bounds__(1024) void k_scan1(const int* __restrict__ cnt,
                                                int* __restrict__ roff,
                                                int* __restrict__ partials, int nn) {
  __shared__ int part[1024];
  const int t = threadIdx.x;
  const int idx = blockIdx.x * 1024 + t;
  int v = (idx < nn) ? cnt[idx] : 0;
  part[t] = v;
  __syncthreads();
  for (int off = 1; off < 1024; off <<= 1) {
    int x = (t >= off) ? part[t - off] : 0;
    __syncthreads();
    part[t] += x;
    __syncthreads();
  }
  if (idx < nn) roff[idx] = part[t] - v;
  if (t == 1023) partials[blockIdx.x] = part[1023];
}

__global__ __launch_bounds__(128) void k_scan2(int* __restrict__ partials, int nb) {
  __shared__ int part[128];
  const int t = threadIdx.x;
  int v = (t < nb) ? partials[t] : 0;
  part[t] = v;
  __syncthreads();
  for (int off = 1; off < 128; off <<= 1) {
    int x = (t >= off) ? part[t - off] : 0;
    __syncthreads();
    part[t] += x;
    __syncthreads();
  }
  if (t < nb) partials[t] = part[t] - v;
}

__global__ __launch_bounds__(1024) void k_scan3(int* __restrict__ roff,
                                                int* __restrict__ cur,
                                                const int* __restrict__ partials,
                                                int nn, int netot) {
  int idx = blockIdx.x * 1024 + threadIdx.x;
  if (idx < nn) {
    int v = roff[idx] + partials[blockIdx.x];
    roff[idx] = v;
    cur[idx] = v;
  }
  if (idx == 0) roff[nn] = netot;
}

__global__ __launch_bounds__(256) void k_fill(const int* __restrict__ s1,
                                              const int* __restrict__ d1,
                                              const int* __restrict__ s2,
                                              const int* __restrict__ d2,
                                              int* __restrict__ cur,
                                              int* __restrict__ ssrc, int netot) {
  int e = blockIdx.x * blockDim.x + threadIdx.x;
  if (e >= netot) return;
  int s, d;
  if (e < NE) { s = s1[e]; d = d1[e]; }
  else        { s = s2[e - NE] + NN; d = d2[e - NE] + NN; }
  int p = atomicAdd(&cur[d], 1);
  ssrc[p] = s;
}

// ---------------- linear: hlin = xin @ W (+ attention dots) ----------------
// 128-row x 128-col tile per 256-thread block; thread = 8 rows x 8 cols.
// Layer 0: xin row n is embed[idx(n)] (gather fused, no staging buffer).
__global__ __launch_bounds__(256) void k_linear(const float* __restrict__ xin,
                                                const int* __restrict__ iA,
                                                const int* __restrict__ iB,
                                                const float* __restrict__ W,
                                                const float* __restrict__ a_src,
                                                const float* __restrict__ a_dst,
                                                float* __restrict__ hlin,
                                                float* __restrict__ asrc,
                                                float* __restrict__ adst, int ntot) {
  __shared__ __align__(16) float w_lds[32 * 128];
  __shared__ __align__(16) float x_lds[128 * 36];
  __shared__ float red_s[512];
  __shared__ float red_d[512];
  const int t = threadIdx.x;
  const int tx = t & 15, ty = t >> 4;
  const int n0 = blockIdx.x * 128;

  float acc[8][8];
#pragma unroll
  for (int r = 0; r < 8; r++)
#pragma unroll
    for (int j = 0; j < 8; j++) acc[r][j] = 0.f;

  for (int kc = 0; kc < 128; kc += 32) {
#pragma unroll
    for (int i = 0; i < 4; i++) {
      int idx = i * 256 + t;  // 1024 float4 of W chunk
      int kr = idx >> 5, c4 = idx & 31;
      ((float4*)w_lds)[kr * 32 + c4] = ((const float4*)W)[(kc + kr) * 32 + c4];
    }
#pragma unroll
    for (int i = 0; i < 4; i++) {
      int idx = i * 256 + t;  // 1024 float4 of x chunk (128 rows x 8 k4)
      int r = idx >> 3, k4 = idx & 7;
      int n = n0 + r;
      float4 v = make_float4(0.f, 0.f, 0.f, 0.f);
      if (n < ntot) {
        int row = n;
        if (iA) row = (n < NN) ? iA[n] : iB[n - NN];
        v = ((const float4*)xin)[(size_t)row * 32 + (kc >> 2) + k4];
      }
      *((float4*)&x_lds[r * 36 + k4 * 4]) = v;
    }
    __syncthreads();
#pragma unroll
    for (int kk = 0; kk < 32; kk += 4) {
      float4 xv[8];
#pragma unroll
      for (int rr = 0; rr < 8; rr++)
        xv[rr] = *((const float4*)&x_lds[(ty * 8 + rr) * 36 + kk]);
#pragma unroll
      for (int q = 0; q < 4; q++) {
        int k = kk + q;
        float4 w0 = ((const float4*)w_lds)[k * 32 + tx];
        float4 w1 = ((const float4*)w_lds)[k * 32 + 16 + tx];
#pragma unroll
        for (int rr = 0; rr < 8; rr++) {
          float xs = q == 0 ? xv[rr].x : q == 1 ? xv[rr].y : q == 2 ? xv[rr].z : xv[rr].w;
          acc[rr][0] += xs * w0.x;
          acc[rr][1] += xs * w0.y;
          acc[rr][2] += xs * w0.z;
          acc[rr][3] += xs * w0.w;
          acc[rr][4] += xs * w1.x;
          acc[rr][5] += xs * w1.y;
          acc[rr][6] += xs * w1.z;
          acc[rr][7] += xs * w1.w;
        }
      }
    }
    __syncthreads();
  }

  red_s[t] = 0.f; red_s[t + 256] = 0.f;
  red_d[t] = 0.f; red_d[t + 256] = 0.f;
  __syncthreads();
  const int hA = tx >> 3, hB = 2 + (tx >> 3);
#pragma unroll
  for (int rr = 0; rr < 8; rr++) {
    int n = n0 + ty * 8 + rr;
    if (n < ntot) {
      float4 o0 = make_float4(acc[rr][0], acc[rr][1], acc[rr][2], acc[rr][3]);
      float4 o1 = make_float4(acc[rr][4], acc[rr][5], acc[rr][6], acc[rr][7]);
      ((float4*)hlin)[(size_t)n * 32 + tx] = o0;
      ((float4*)hlin)[(size_t)n * 32 + 16 + tx] = o1;
      float sA = 0.f, sB = 0.f, dA = 0.f, dB = 0.f;
#pragma unroll
      for (int j = 0; j < 4; j++) {
        sA += acc[rr][j] * a_src[tx * 4 + j];
        dA += acc[rr][j] * a_dst[tx * 4 + j];
        sB += acc[rr][4 + j] * a_src[64 + tx * 4 + j];
        dB += acc[rr][4 + j] * a_dst[64 + tx * 4 + j];
      }
      int r = ty * 8 + rr;
      atomicAdd(&red_s[r * 4 + hA], sA);
      atomicAdd(&red_s[r * 4 + hB], sB);
      atomicAdd(&red_d[r * 4 + hA], dA);
      atomicAdd(&red_d[r * 4 + hB], dB);
    }
  }
  __syncthreads();
#pragma unroll
  for (int i = 0; i < 2; i++) {
    int idx = i * 256 + t;
    int r = idx >> 2, hd = idx & 3;
    int n = n0 + r;
    if (n < ntot) {
      asrc[n * 4 + hd] = red_s[idx];
      adst[n * 4 + hd] = red_d[idx];
    }
  }
}

// ---------------- aggregate: one wave per destination node ----------------
// lane = (head hh = lane>>4, edge-slot sub = lane&15); softmax without
// max-subtraction; denominator accumulated inside the PV loop; exact-count
// gather loop (cnt is wave-uniform -> uniform branches).
__global__ __launch_bounds__(256) void k_aggregate(const float* __restrict__ hlin,
                                                   const float* __restrict__ asrcv,
                                                   const float* __restrict__ adstv,
                                                   const int* __restrict__ roff,
                                                   const int* __restrict__ ssrc,
                                                   const float* __restrict__ bias,
                                                   float* __restrict__ hout, int ntot) {
  const int lane = threadIdx.x & 63;
  const int n = blockIdx.x * 4 + (threadIdx.x >> 6);
  if (n >= ntot) return;
  const int hh = lane >> 4;
  const int sub = lane & 15;
  const int sb = lane & 48;
  const int beg = roff[n], end = roff[n + 1];
  const int deg = end - beg;

  const float adh = adstv[n * 4 + hh];
  const float ash = asrcv[n * 4 + hh];
  const float pself = __expf(leaky(ash + adh));

  const int c0 = lane * 2;
  float2 hv = ((const float2*)hlin)[(size_t)n * 64 + lane];
  float acc0 = pself * hv.x, acc1 = pself * hv.y;
  float dh = pself;

  for (int base = 0; base < deg; base += 16) {
    int cnt = deg - base; if (cnt > 16) cnt = 16;
    int s = 0;
    float px = 0.f;
    if (sub < cnt) {
      s = ssrc[beg + base + sub];
      px = __expf(leaky(asrcv[s * 4 + hh] + adh));
    }
#pragma unroll 8
    for (int j = 0; j < cnt; j++) {
      int sj = __shfl(s, sb + j);
      float exj = __shfl(px, sb + j);
      float2 hs = ((const float2*)hlin)[(size_t)sj * 64 + lane];
      acc0 += exj * hs.x;
      acc1 += exj * hs.y;
      dh += exj;
    }
  }
  float inv = 1.f / (dh + GEPS);
  float o0 = fmaxf(acc0 * inv + bias[c0], 0.f);
  float o1 = fmaxf(acc1 * inv + bias[c0 + 1], 0.f);
  hout[(size_t)n * DIM + c0] = o0;
  hout[(size_t)n * DIM + c0 + 1] = o1;
}

// ---------------- global attention pooling ----------------
__global__ __launch_bounds__(256) void k_pool(const float* __restrict__ h,
                                              const float* __restrict__ gate_w,
                                              const float* __restrict__ gate_b,
                                              float* __restrict__ acc_out) {
  const int lane = threadIdx.x & 63;
  const int widg = blockIdx.x * 4 + (threadIdx.x >> 6);
  const int nw = gridDim.x * 4;
  const float w0 = gate_w[lane * 2], w1 = gate_w[lane * 2 + 1];
  const float gb = gate_b[0];
  float acc0 = 0.f, acc1 = 0.f, se = 0.f;
  for (int n = widg; n < NN; n += nw) {
    float2 hv = ((const float2*)h)[(size_t)n * 64 + lane];
    float p = hv.x * w0 + hv.y * w1;
#pragma unroll
    for (int off = 1; off < 64; off <<= 1) p += __shfl_xor(p, off);
    float sg = 1.f / (1.f + __expf(-(p + gb)));
    float e = __expf(sg);
    se += e;
    acc0 += e * hv.x;
    acc1 += e * hv.y;
  }
  atomicAdd(&acc_out[lane * 2], acc0);
  atomicAdd(&acc_out[lane * 2 + 1], acc1);
  if (lane == 0) atomicAdd(&acc_out[128], se);
}

// ---------------- final MLP ----------------
__global__ __launch_bounds__(128) void k_mlp(const float* __restrict__ p1,
                                             const float* __restrict__ p2,
                                             const float* __restrict__ fc1_w,
                                             const float* __restrict__ fc1_b,
                                             const float* __restrict__ fc2_w,
                                             const float* __restrict__ fc2_b,
                                             float* __restrict__ out) {
  __shared__ float cat[256];
  __shared__ float red[2];
  const int t = threadIdx.x;
  cat[t] = p1[t] / p1[128];
  cat[128 + t] = p2[t] / p2[128];
  __syncthreads();
  float a = fc1_b[t];
  for (int k = 0; k < 256; k++) a += cat[k] * fc1_w[k * 128 + t];
  a = fmaxf(a, 0.f);
  float v = a * fc2_w[t];
#pragma unroll
  for (int off = 1; off < 64; off <<= 1) v += __shfl_xor(v, off);
  if ((t & 63) == 0) red[t >> 6] = v;
  __syncthreads();
  if (t == 0) out[0] = red[0] + red[1] + fc2_b[0];
}

extern "C" void kernel_launch(void* const* d_in, const int* in_sizes, int n_in,
                              void* d_out, int out_size, void* d_ws, size_t ws_size,
                              hipStream_t stream) {
  (void)in_sizes; (void)n_in; (void)out_size;
  const int* x1 = (const int*)d_in[0];
  const int* x2 = (const int*)d_in[1];
  const int* ei1 = (const int*)d_in[2];
  const int* ei2 = (const int*)d_in[3];
  const float* embed = (const float*)d_in[4];
  const float* W = (const float*)d_in[5];
  const float* attS = (const float*)d_in[6];
  const float* attD = (const float*)d_in[7];
  const float* bias = (const float*)d_in[8];
  const float* gw = (const float*)d_in[9];
  const float* gb = (const float*)d_in[10];
  const float* f1w = (const float*)d_in[11];
  const float* f1b = (const float*)d_in[12];
  const float* f2w = (const float*)d_in[13];
  const float* f2b = (const float*)d_in[14];
  float* out = (float*)d_out;

  auto req = [](int nt, int net) {
    size_t s = 0;
    auto pad = [&](size_t b) { s = (s + b + 255) & ~size_t(255); };
    pad(size_t(nt) * DIM * 4);
    pad(size_t(nt) * DIM * 4);
    pad(size_t(nt) * 16);
    pad(size_t(nt) * 16);
    pad(size_t(nt + 1) * 4);
    pad(size_t(nt) * 4);
    pad(size_t(net) * 4);
    pad(128 * 4);
    pad(2 * 129 * 4);
    return s;
  };
  const bool combined = ws_size >= req(2 * NN, 2 * NE);
  const int nt = combined ? 2 * NN : NN;
  const int net = combined ? 2 * NE : NE;

  char* ws = (char*)d_ws;
  size_t off = 0;
  auto alloc = [&](size_t bytes) {
    void* p = ws + off;
    off = (off + bytes + 255) & ~size_t(255);
    return p;
  };
  float* h_in = (float*)alloc(size_t(nt) * DIM * 4);
  float* h_lin = (float*)alloc(size_t(nt) * DIM * 4);
  float* asrc = (float*)alloc(size_t(nt) * 16);
  float* adst = (float*)alloc(size_t(nt) * 16);
  int* roff = (int*)alloc(size_t(nt + 1) * 4);
  int* cur = (int*)alloc(size_t(nt) * 4);
  int* ssrc = (int*)alloc(size_t(net) * 4);
  int* partials = (int*)alloc(128 * 4);
  float* pool = (float*)alloc(2 * 129 * 4);

  hipMemsetAsync(pool, 0, 2 * 129 * 4, stream);

  const int nb = (nt + 1023) / 1024;
  const int lgrid = (nt + 127) / 128;

  auto run_graphs = [&](const int* xA, const int* xB, const int* eA, const int* eB) {
    hipMemsetAsync(cur, 0, size_t(nt) * 4, stream);
    k_count<<<(net + 255) / 256, 256, 0, stream>>>(eA + NE, eB + NE, cur, net);
    k_scan1<<<nb, 1024, 0, stream>>>(cur, roff, partials, nt);
    k_scan2<<<1, 128, 0, stream>>>(partials, nb);
    k_scan3<<<nb, 1024, 0, stream>>>(roff, cur, partials, nt, net);
    k_fill<<<(net + 255) / 256, 256, 0, stream>>>(eA, eA + NE, eB, eB + NE, cur, ssrc, net);
    for (int l = 0; l < 3; ++l) {
      if (l == 0) {
        k_linear<<<lgrid, 256, 0, stream>>>(
            embed, xA, xB, W, attS, attD, h_lin, asrc, adst, nt);
      } else {
        k_linear<<<lgrid, 256, 0, stream>>>(
            h_in, nullptr, nullptr, W + l * DIM * DIM, attS + l * DIM, attD + l * DIM,
            h_lin, asrc, adst, nt);
      }
      k_aggregate<<<(nt + 3) / 4, 256, 0, stream>>>(
          h_lin, asrc, adst, roff, ssrc, bias + l * DIM, h_in, nt);
    }
  };

  if (combined) {
    run_graphs(x1, x2, ei1, ei2);
    k_pool<<<128, 256, 0, stream>>>(h_in, gw, gb, pool);
    k_pool<<<128, 256, 0, stream>>>(h_in + size_t(NN) * DIM, gw, gb, pool + 129);
  } else {
    run_graphs(x1, x1, ei1, ei1);
    k_pool<<<128, 256, 0, stream>>>(h_in, gw, gb, pool);
    run_graphs(x2, x2, ei2, ei2);
    k_pool<<<128, 256, 0, stream>>>(h_in, gw, gb, pool + 129);
  }
  k_mlp<<<1, 128, 0, stream>>>(pool, pool + 129, f1w, f1b, f2w, f2b, out);
}

// Round 5
// 902.745 us; speedup vs baseline: 1.1439x; 1.1439x over previous
//
#include <hip/hip_runtime.h>
#include <hip/hip_bf16.h>

#define NN 50000
#define NE 600000
#define DIM 128
#define NEG 0.2f
#define GEPS 1e-16f

__device__ __forceinline__ float leaky(float x) { return x > 0.f ? x : NEG * x; }

// ---------------- CSR build ----------------
__global__ __launch_bounds__(256) void k_count(const int* __restrict__ d1,
                                               const int* __restrict__ d2,
                                               int* __restrict__ cnt, int netot) {
  int e = blockIdx.x * blockDim.x + threadIdx.x;
  if (e >= netot) return;
  int dst = (e < NE) ? d1[e] : d2[e - NE] + NN;
  atomicAdd(&cnt[dst], 1);
}

__global__ __launch_bounds__(1024) void k_scan1(const int* __restrict__ cnt,
                                                int* __restrict__ roff,
                                                int* __restrict__ partials, int nn) {
  __shared__ int part[1024];
  const int t = threadIdx.x;
  const int idx = blockIdx.x * 1024 + t;
  int v = (idx < nn) ? cnt[idx] : 0;
  part[t] = v;
  __syncthreads();
  for (int off = 1; off < 1024; off <<= 1) {
    int x = (t >= off) ? part[t - off] : 0;
    __syncthreads();
    part[t] += x;
    __syncthreads();
  }
  if (idx < nn) roff[idx] = part[t] - v;
  if (t == 1023) partials[blockIdx.x] = part[1023];
}

__global__ __launch_bounds__(128) void k_scan2(int* __restrict__ partials, int nb) {
  __shared__ int part[128];
  const int t = threadIdx.x;
  int v = (t < nb) ? partials[t] : 0;
  part[t] = v;
  __syncthreads();
  for (int off = 1; off < 128; off <<= 1) {
    int x = (t >= off) ? part[t - off] : 0;
    __syncthreads();
    part[t] += x;
    __syncthreads();
  }
  if (t < nb) partials[t] = part[t] - v;
}

__global__ __launch_bounds__(1024) void k_scan3(int* __restrict__ roff,
                                                int* __restrict__ cur,
                                                const int* __restrict__ partials,
                                                int nn, int netot) {
  int idx = blockIdx.x * 1024 + threadIdx.x;
  if (idx < nn) {
    int v = roff[idx] + partials[blockIdx.x];
    roff[idx] = v;
    cur[idx] = v;
  }
  if (idx == 0) roff[nn] = netot;
}

__global__ __launch_bounds__(256) void k_fill(const int* __restrict__ s1,
                                              const int* __restrict__ d1,
                                              const int* __restrict__ s2,
                                              const int* __restrict__ d2,
                                              int* __restrict__ cur,
                                              int* __restrict__ ssrc, int netot) {
  int e = blockIdx.x * blockDim.x + threadIdx.x;
  if (e >= netot) return;
  int s, d;
  if (e < NE) { s = s1[e]; d = d1[e]; }
  else        { s = s2[e - NE] + NN; d = d2[e - NE] + NN; }
  int p = atomicAdd(&cur[d], 1);
  ssrc[p] = s;
}

// ---------------- linear: hlin = xin @ W (+ attention dots) ----------------
// 64-row x 128-col tile per 256-thread block (measured-best occupancy);
// thread = 4 rows x 8 cols. Layer 0: row n is embed[idx(n)] (fused gather).
__global__ __launch_bounds__(256) void k_linear(const float* __restrict__ xin,
                                                const int* __restrict__ iA,
                                                const int* __restrict__ iB,
                                                const float* __restrict__ W,
                                                const float* __restrict__ a_src,
                                                const float* __restrict__ a_dst,
                                                float* __restrict__ hlin,
                                                float* __restrict__ asrc,
                                                float* __restrict__ adst, int ntot) {
  __shared__ __align__(16) float w_lds[32 * 128];
  __shared__ __align__(16) float x_lds[64 * 36];
  __shared__ float red_s[256];
  __shared__ float red_d[256];
  const int t = threadIdx.x;
  const int tx = t & 15, ty = t >> 4;
  const int n0 = blockIdx.x * 64;

  float acc[4][8];
#pragma unroll
  for (int r = 0; r < 4; r++)
#pragma unroll
    for (int j = 0; j < 8; j++) acc[r][j] = 0.f;

  for (int kc = 0; kc < 128; kc += 32) {
#pragma unroll
    for (int i = 0; i < 4; i++) {
      int idx = i * 256 + t;  // 1024 float4 of W chunk
      int kr = idx >> 5, c4 = idx & 31;
      ((float4*)w_lds)[kr * 32 + c4] = ((const float4*)W)[(kc + kr) * 32 + c4];
    }
#pragma unroll
    for (int i = 0; i < 2; i++) {
      int idx = i * 256 + t;  // 512 float4 of x chunk (64 rows x 8 k4)
      int r = idx >> 3, k4 = idx & 7;
      int n = n0 + r;
      float4 v = make_float4(0.f, 0.f, 0.f, 0.f);
      if (n < ntot) {
        int row = n;
        if (iA) row = (n < NN) ? iA[n] : iB[n - NN];
        v = ((const float4*)xin)[(size_t)row * 32 + (kc >> 2) + k4];
      }
      *((float4*)&x_lds[r * 36 + k4 * 4]) = v;
    }
    __syncthreads();
#pragma unroll
    for (int kk = 0; kk < 32; kk += 4) {
      float4 xv[4];
#pragma unroll
      for (int rr = 0; rr < 4; rr++)
        xv[rr] = *((const float4*)&x_lds[(ty * 4 + rr) * 36 + kk]);
#pragma unroll
      for (int q = 0; q < 4; q++) {
        int k = kk + q;
        float4 w0 = ((const float4*)w_lds)[k * 32 + tx];
        float4 w1 = ((const float4*)w_lds)[k * 32 + 16 + tx];
#pragma unroll
        for (int rr = 0; rr < 4; rr++) {
          float xs = q == 0 ? xv[rr].x : q == 1 ? xv[rr].y : q == 2 ? xv[rr].z : xv[rr].w;
          acc[rr][0] += xs * w0.x;
          acc[rr][1] += xs * w0.y;
          acc[rr][2] += xs * w0.z;
          acc[rr][3] += xs * w0.w;
          acc[rr][4] += xs * w1.x;
          acc[rr][5] += xs * w1.y;
          acc[rr][6] += xs * w1.z;
          acc[rr][7] += xs * w1.w;
        }
      }
    }
    __syncthreads();
  }

  red_s[t] = 0.f;
  red_d[t] = 0.f;
  __syncthreads();
  const int hA = tx >> 3, hB = 2 + (tx >> 3);
#pragma unroll
  for (int rr = 0; rr < 4; rr++) {
    int n = n0 + ty * 4 + rr;
    if (n < ntot) {
      float4 o0 = make_float4(acc[rr][0], acc[rr][1], acc[rr][2], acc[rr][3]);
      float4 o1 = make_float4(acc[rr][4], acc[rr][5], acc[rr][6], acc[rr][7]);
      ((float4*)hlin)[(size_t)n * 32 + tx] = o0;
      ((float4*)hlin)[(size_t)n * 32 + 16 + tx] = o1;
      float sA = 0.f, sB = 0.f, dA = 0.f, dB = 0.f;
#pragma unroll
      for (int j = 0; j < 4; j++) {
        sA += acc[rr][j] * a_src[tx * 4 + j];
        dA += acc[rr][j] * a_dst[tx * 4 + j];
        sB += acc[rr][4 + j] * a_src[64 + tx * 4 + j];
        dB += acc[rr][4 + j] * a_dst[64 + tx * 4 + j];
      }
      int r = ty * 4 + rr;
      atomicAdd(&red_s[r * 4 + hA], sA);
      atomicAdd(&red_s[r * 4 + hB], sB);
      atomicAdd(&red_d[r * 4 + hA], dA);
      atomicAdd(&red_d[r * 4 + hB], dB);
    }
  }
  __syncthreads();
  {
    int r = t >> 2, hd = t & 3;
    int n = n0 + r;
    if (n < ntot) {
      asrc[n * 4 + hd] = red_s[t];
      adst[n * 4 + hd] = red_d[t];
    }
  }
}

// ---------------- aggregate: one wave per destination node ----------------
// lane = (head hh = lane>>4, edge-slot sub = lane&15); softmax without
// max-subtraction; denominator accumulated inside the PV loop; exact-count
// gather loop (cnt is wave-uniform -> uniform branches).
__global__ __launch_bounds__(256) void k_aggregate(const float* __restrict__ hlin,
                                                   const float* __restrict__ asrcv,
                                                   const float* __restrict__ adstv,
                                                   const int* __restrict__ roff,
                                                   const int* __restrict__ ssrc,
                                                   const float* __restrict__ bias,
                                                   float* __restrict__ hout, int ntot) {
  const int lane = threadIdx.x & 63;
  const int n = blockIdx.x * 4 + (threadIdx.x >> 6);
  if (n >= ntot) return;
  const int hh = lane >> 4;
  const int sub = lane & 15;
  const int sb = lane & 48;
  const int beg = roff[n], end = roff[n + 1];
  const int deg = end - beg;

  const float adh = adstv[n * 4 + hh];
  const float ash = asrcv[n * 4 + hh];
  const float pself = __expf(leaky(ash + adh));

  const int c0 = lane * 2;
  float2 hv = ((const float2*)hlin)[(size_t)n * 64 + lane];
  float acc0 = pself * hv.x, acc1 = pself * hv.y;
  float dh = pself;

  for (int base = 0; base < deg; base += 16) {
    int cnt = deg - base; if (cnt > 16) cnt = 16;
    int s = 0;
    float px = 0.f;
    if (sub < cnt) {
      s = ssrc[beg + base + sub];
      px = __expf(leaky(asrcv[s * 4 + hh] + adh));
    }
#pragma unroll 8
    for (int j = 0; j < cnt; j++) {
      int sj = __shfl(s, sb + j);
      float exj = __shfl(px, sb + j);
      float2 hs = ((const float2*)hlin)[(size_t)sj * 64 + lane];
      acc0 += exj * hs.x;
      acc1 += exj * hs.y;
      dh += exj;
    }
  }
  float inv = 1.f / (dh + GEPS);
  float o0 = fmaxf(acc0 * inv + bias[c0], 0.f);
  float o1 = fmaxf(acc1 * inv + bias[c0 + 1], 0.f);
  hout[(size_t)n * DIM + c0] = o0;
  hout[(size_t)n * DIM + c0 + 1] = o1;
}

// ---------------- global attention pooling ----------------
__global__ __launch_bounds__(256) void k_pool(const float* __restrict__ h,
                                              const float* __restrict__ gate_w,
                                              const float* __restrict__ gate_b,
                                              float* __restrict__ acc_out) {
  const int lane = threadIdx.x & 63;
  const int widg = blockIdx.x * 4 + (threadIdx.x >> 6);
  const int nw = gridDim.x * 4;
  const float w0 = gate_w[lane * 2], w1 = gate_w[lane * 2 + 1];
  const float gb = gate_b[0];
  float acc0 = 0.f, acc1 = 0.f, se = 0.f;
  for (int n = widg; n < NN; n += nw) {
    float2 hv = ((const float2*)h)[(size_t)n * 64 + lane];
    float p = hv.x * w0 + hv.y * w1;
#pragma unroll
    for (int off = 1; off < 64; off <<= 1) p += __shfl_xor(p, off);
    float sg = 1.f / (1.f + __expf(-(p + gb)));
    float e = __expf(sg);
    se += e;
    acc0 += e * hv.x;
    acc1 += e * hv.y;
  }
  atomicAdd(&acc_out[lane * 2], acc0);
  atomicAdd(&acc_out[lane * 2 + 1], acc1);
  if (lane == 0) atomicAdd(&acc_out[128], se);
}

// ---------------- final MLP ----------------
__global__ __launch_bounds__(128) void k_mlp(const float* __restrict__ p1,
                                             const float* __restrict__ p2,
                                             const float* __restrict__ fc1_w,
                                             const float* __restrict__ fc1_b,
                                             const float* __restrict__ fc2_w,
                                             const float* __restrict__ fc2_b,
                                             float* __restrict__ out) {
  __shared__ float cat[256];
  __shared__ float red[2];
  const int t = threadIdx.x;
  cat[t] = p1[t] / p1[128];
  cat[128 + t] = p2[t] / p2[128];
  __syncthreads();
  float a = fc1_b[t];
  for (int k = 0; k < 256; k++) a += cat[k] * fc1_w[k * 128 + t];
  a = fmaxf(a, 0.f);
  float v = a * fc2_w[t];
#pragma unroll
  for (int off = 1; off < 64; off <<= 1) v += __shfl_xor(v, off);
  if ((t & 63) == 0) red[t >> 6] = v;
  __syncthreads();
  if (t == 0) out[0] = red[0] + red[1] + fc2_b[0];
}

extern "C" void kernel_launch(void* const* d_in, const int* in_sizes, int n_in,
                              void* d_out, int out_size, void* d_ws, size_t ws_size,
                              hipStream_t stream) {
  (void)in_sizes; (void)n_in; (void)out_size;
  const int* x1 = (const int*)d_in[0];
  const int* x2 = (const int*)d_in[1];
  const int* ei1 = (const int*)d_in[2];
  const int* ei2 = (const int*)d_in[3];
  const float* embed = (const float*)d_in[4];
  const float* W = (const float*)d_in[5];
  const float* attS = (const float*)d_in[6];
  const float* attD = (const float*)d_in[7];
  const float* bias = (const float*)d_in[8];
  const float* gw = (const float*)d_in[9];
  const float* gb = (const float*)d_in[10];
  const float* f1w = (const float*)d_in[11];
  const float* f1b = (const float*)d_in[12];
  const float* f2w = (const float*)d_in[13];
  const float* f2b = (const float*)d_in[14];
  float* out = (float*)d_out;

  auto req = [](int nt, int net) {
    size_t s = 0;
    auto pad = [&](size_t b) { s = (s + b + 255) & ~size_t(255); };
    pad(size_t(nt) * DIM * 4);
    pad(size_t(nt) * DIM * 4);
    pad(size_t(nt) * 16);
    pad(size_t(nt) * 16);
    pad(size_t(nt + 1) * 4);
    pad(size_t(nt) * 4);
    pad(size_t(net) * 4);
    pad(128 * 4);
    pad(2 * 129 * 4);
    return s;
  };
  const bool combined = ws_size >= req(2 * NN, 2 * NE);
  const int nt = combined ? 2 * NN : NN;
  const int net = combined ? 2 * NE : NE;

  char* ws = (char*)d_ws;
  size_t off = 0;
  auto alloc = [&](size_t bytes) {
    void* p = ws + off;
    off = (off + bytes + 255) & ~size_t(255);
    return p;
  };
  float* h_in = (float*)alloc(size_t(nt) * DIM * 4);
  float* h_lin = (float*)alloc(size_t(nt) * DIM * 4);
  float* asrc = (float*)alloc(size_t(nt) * 16);
  float* adst = (float*)alloc(size_t(nt) * 16);
  int* roff = (int*)alloc(size_t(nt + 1) * 4);
  int* cur = (int*)alloc(size_t(nt) * 4);
  int* ssrc = (int*)alloc(size_t(net) * 4);
  int* partials = (int*)alloc(128 * 4);
  float* pool = (float*)alloc(2 * 129 * 4);

  hipMemsetAsync(pool, 0, 2 * 129 * 4, stream);

  const int nb = (nt + 1023) / 1024;
  const int lgrid = (nt + 63) / 64;

  auto run_graphs = [&](const int* xA, const int* xB, const int* eA, const int* eB) {
    hipMemsetAsync(cur, 0, size_t(nt) * 4, stream);
    k_count<<<(net + 255) / 256, 256, 0, stream>>>(eA + NE, eB + NE, cur, net);
    k_scan1<<<nb, 1024, 0, stream>>>(cur, roff, partials, nt);
    k_scan2<<<1, 128, 0, stream>>>(partials, nb);
    k_scan3<<<nb, 1024, 0, stream>>>(roff, cur, partials, nt, net);
    k_fill<<<(net + 255) / 256, 256, 0, stream>>>(eA, eA + NE, eB, eB + NE, cur, ssrc, net);
    for (int l = 0; l < 3; ++l) {
      if (l == 0) {
        k_linear<<<lgrid, 256, 0, stream>>>(
            embed, xA, xB, W, attS, attD, h_lin, asrc, adst, nt);
      } else {
        k_linear<<<lgrid, 256, 0, stream>>>(
            h_in, nullptr, nullptr, W + l * DIM * DIM, attS + l * DIM, attD + l * DIM,
            h_lin, asrc, adst, nt);
      }
      k_aggregate<<<(nt + 3) / 4, 256, 0, stream>>>(
          h_lin, asrc, adst, roff, ssrc, bias + l * DIM, h_in, nt);
    }
  };

  if (combined) {
    run_graphs(x1, x2, ei1, ei2);
    k_pool<<<128, 256, 0, stream>>>(h_in, gw, gb, pool);
    k_pool<<<128, 256, 0, stream>>>(h_in + size_t(NN) * DIM, gw, gb, pool + 129);
  } else {
    run_graphs(x1, x1, ei1, ei1);
    k_pool<<<128, 256, 0, stream>>>(h_in, gw, gb, pool);
    run_graphs(x2, x2, ei2, ei2);
    k_pool<<<128, 256, 0, stream>>>(h_in, gw, gb, pool + 129);
  }
  k_mlp<<<1, 128, 0, stream>>>(pool, pool + 129, f1w, f1b, f2w, f2b, out);
}

// Round 6
// 870.378 us; speedup vs baseline: 1.1865x; 1.0372x over previous
//
#include <hip/hip_runtime.h>
#include <hip/hip_bf16.h>

#define NN 50000
#define NE 600000
#define DIM 128
#define NEG 0.2f
#define GEPS 1e-16f

__device__ __forceinline__ float leaky(float x) { return x > 0.f ? x : NEG * x; }

// ---------------- CSR build ----------------
__global__ __launch_bounds__(256) void k_count(const int* __restrict__ d1,
                                               const int* __restrict__ d2,
                                               int* __restrict__ cnt, int netot) {
  int e = blockIdx.x * blockDim.x + threadIdx.x;
  if (e >= netot) return;
  int dst = (e < NE) ? d1[e] : d2[e - NE] + NN;
  atomicAdd(&cnt[dst], 1);
}

__global__ __launch_bounds__(1024) void k_scan1(const int* __restrict__ cnt,
                                                int* __restrict__ roff,
                                                int* __restrict__ partials, int nn) {
  __shared__ int part[1024];
  const int t = threadIdx.x;
  const int idx = blockIdx.x * 1024 + t;
  int v = (idx < nn) ? cnt[idx] : 0;
  part[t] = v;
  __syncthreads();
  for (int off = 1; off < 1024; off <<= 1) {
    int x = (t >= off) ? part[t - off] : 0;
    __syncthreads();
    part[t] += x;
    __syncthreads();
  }
  if (idx < nn) roff[idx] = part[t] - v;
  if (t == 1023) partials[blockIdx.x] = part[1023];
}

__global__ __launch_bounds__(128) void k_scan2(int* __restrict__ partials, int nb) {
  __shared__ int part[128];
  const int t = threadIdx.x;
  int v = (t < nb) ? partials[t] : 0;
  part[t] = v;
  __syncthreads();
  for (int off = 1; off < 128; off <<= 1) {
    int x = (t >= off) ? part[t - off] : 0;
    __syncthreads();
    part[t] += x;
    __syncthreads();
  }
  if (t < nb) partials[t] = part[t] - v;
}

__global__ __launch_bounds__(1024) void k_scan3(int* __restrict__ roff,
                                                int* __restrict__ cur,
                                                const int* __restrict__ partials,
                                                int nn, int netot) {
  int idx = blockIdx.x * 1024 + threadIdx.x;
  if (idx < nn) {
    int v = roff[idx] + partials[blockIdx.x];
    roff[idx] = v;
    cur[idx] = v;
  }
  if (idx == 0) roff[nn] = netot;
}

__global__ __launch_bounds__(256) void k_fill(const int* __restrict__ s1,
                                              const int* __restrict__ d1,
                                              const int* __restrict__ s2,
                                              const int* __restrict__ d2,
                                              int* __restrict__ cur,
                                              int* __restrict__ ssrc, int netot) {
  int e = blockIdx.x * blockDim.x + threadIdx.x;
  if (e >= netot) return;
  int s, d;
  if (e < NE) { s = s1[e]; d = d1[e]; }
  else        { s = s2[e - NE] + NN; d = d2[e - NE] + NN; }
  int p = atomicAdd(&cur[d], 1);
  ssrc[p] = s;
}

// ---------------- linear: hlin = xin @ W (+ attention dots) ----------------
// 64-row x 128-col tile per 256-thread block (measured-best occupancy);
// thread = 4 rows x 8 cols. Layer 0: row n is embed[idx(n)] (fused gather).
__global__ __launch_bounds__(256) void k_linear(const float* __restrict__ xin,
                                                const int* __restrict__ iA,
                                                const int* __restrict__ iB,
                                                const float* __restrict__ W,
                                                const float* __restrict__ a_src,
                                                const float* __restrict__ a_dst,
                                                float* __restrict__ hlin,
                                                float* __restrict__ asrc,
                                                float* __restrict__ adst, int ntot) {
  __shared__ __align__(16) float w_lds[32 * 128];
  __shared__ __align__(16) float x_lds[64 * 36];
  __shared__ float red_s[256];
  __shared__ float red_d[256];
  const int t = threadIdx.x;
  const int tx = t & 15, ty = t >> 4;
  const int n0 = blockIdx.x * 64;

  float acc[4][8];
#pragma unroll
  for (int r = 0; r < 4; r++)
#pragma unroll
    for (int j = 0; j < 8; j++) acc[r][j] = 0.f;

  for (int kc = 0; kc < 128; kc += 32) {
#pragma unroll
    for (int i = 0; i < 4; i++) {
      int idx = i * 256 + t;  // 1024 float4 of W chunk
      int kr = idx >> 5, c4 = idx & 31;
      ((float4*)w_lds)[kr * 32 + c4] = ((const float4*)W)[(kc + kr) * 32 + c4];
    }
#pragma unroll
    for (int i = 0; i < 2; i++) {
      int idx = i * 256 + t;  // 512 float4 of x chunk (64 rows x 8 k4)
      int r = idx >> 3, k4 = idx & 7;
      int n = n0 + r;
      float4 v = make_float4(0.f, 0.f, 0.f, 0.f);
      if (n < ntot) {
        int row = n;
        if (iA) row = (n < NN) ? iA[n] : iB[n - NN];
        v = ((const float4*)xin)[(size_t)row * 32 + (kc >> 2) + k4];
      }
      *((float4*)&x_lds[r * 36 + k4 * 4]) = v;
    }
    __syncthreads();
#pragma unroll
    for (int kk = 0; kk < 32; kk += 4) {
      float4 xv[4];
#pragma unroll
      for (int rr = 0; rr < 4; rr++)
        xv[rr] = *((const float4*)&x_lds[(ty * 4 + rr) * 36 + kk]);
#pragma unroll
      for (int q = 0; q < 4; q++) {
        int k = kk + q;
        float4 w0 = ((const float4*)w_lds)[k * 32 + tx];
        float4 w1 = ((const float4*)w_lds)[k * 32 + 16 + tx];
#pragma unroll
        for (int rr = 0; rr < 4; rr++) {
          float xs = q == 0 ? xv[rr].x : q == 1 ? xv[rr].y : q == 2 ? xv[rr].z : xv[rr].w;
          acc[rr][0] += xs * w0.x;
          acc[rr][1] += xs * w0.y;
          acc[rr][2] += xs * w0.z;
          acc[rr][3] += xs * w0.w;
          acc[rr][4] += xs * w1.x;
          acc[rr][5] += xs * w1.y;
          acc[rr][6] += xs * w1.z;
          acc[rr][7] += xs * w1.w;
        }
      }
    }
    __syncthreads();
  }

  red_s[t] = 0.f;
  red_d[t] = 0.f;
  __syncthreads();
  const int hA = tx >> 3, hB = 2 + (tx >> 3);
#pragma unroll
  for (int rr = 0; rr < 4; rr++) {
    int n = n0 + ty * 4 + rr;
    if (n < ntot) {
      float4 o0 = make_float4(acc[rr][0], acc[rr][1], acc[rr][2], acc[rr][3]);
      float4 o1 = make_float4(acc[rr][4], acc[rr][5], acc[rr][6], acc[rr][7]);
      ((float4*)hlin)[(size_t)n * 32 + tx] = o0;
      ((float4*)hlin)[(size_t)n * 32 + 16 + tx] = o1;
      float sA = 0.f, sB = 0.f, dA = 0.f, dB = 0.f;
#pragma unroll
      for (int j = 0; j < 4; j++) {
        sA += acc[rr][j] * a_src[tx * 4 + j];
        dA += acc[rr][j] * a_dst[tx * 4 + j];
        sB += acc[rr][4 + j] * a_src[64 + tx * 4 + j];
        dB += acc[rr][4 + j] * a_dst[64 + tx * 4 + j];
      }
      int r = ty * 4 + rr;
      atomicAdd(&red_s[r * 4 + hA], sA);
      atomicAdd(&red_s[r * 4 + hB], sB);
      atomicAdd(&red_d[r * 4 + hA], dA);
      atomicAdd(&red_d[r * 4 + hB], dB);
    }
  }
  __syncthreads();
  {
    int r = t >> 2, hd = t & 3;
    int n = n0 + r;
    if (n < ntot) {
      asrc[n * 4 + hd] = red_s[t];
      adst[n * 4 + hd] = red_d[t];
    }
  }
}

// ---------------- aggregate v3: one wave per dst node, pair-split halves ----
// lanes 0-31 process even edge slots, 32-63 odd slots; each lane loads float4
// (32 lanes = full 512B row, so one wave load fetches 2 rows). Per 16-edge
// chunk: stage s/px on lane (hs*16+sub), then 8 batched pair-steps with all
// loads issued before consumption (ILP). Softmax without max-subtraction.
__global__ __launch_bounds__(256) void k_aggregate(const float* __restrict__ hlin,
                                                   const float* __restrict__ asrcv,
                                                   const float* __restrict__ adstv,
                                                   const int* __restrict__ roff,
                                                   const int* __restrict__ ssrc,
                                                   const float* __restrict__ bias,
                                                   float* __restrict__ hout, int ntot) {
  const int lane = threadIdx.x & 63;
  const int n = blockIdx.x * 4 + (threadIdx.x >> 6);
  if (n >= ntot) return;
  const int p = lane >> 5;       // half: even/odd edge slots
  const int c = lane & 31;       // float4 column index within row
  const int hc = c >> 3;         // head of this lane's columns
  const int sub = lane & 15;     // staging edge slot
  const int hs = lane >> 4;      // staging head
  const int beg = roff[n], end = roff[n + 1];
  const int deg = end - beg;

  const float adh_hs = adstv[n * 4 + hs];
  const float pselfc = __expf(leaky(asrcv[n * 4 + hc] + adstv[n * 4 + hc]));

  float4 hv = ((const float4*)hlin)[(size_t)n * 32 + c];
  float4 acc;
  float dh;
  if (p == 0) {
    acc = make_float4(pselfc * hv.x, pselfc * hv.y, pselfc * hv.z, pselfc * hv.w);
    dh = pselfc;
  } else {
    acc = make_float4(0.f, 0.f, 0.f, 0.f);
    dh = 0.f;
  }

  for (int base = 0; base < deg; base += 16) {
    int cnt = deg - base; if (cnt > 16) cnt = 16;
    int s = n;        // invalid slots gather the (hot) self row with weight 0
    float px = 0.f;
    if (sub < cnt) {
      s = ssrc[beg + base + sub];
      px = __expf(leaky(asrcv[s * 4 + hs] + adh_hs));
    }
    int sj[8]; float ex[8]; float4 ld[8];
#pragma unroll
    for (int jj = 0; jj < 8; jj++) {
      int e = 2 * jj + p;
      sj[jj] = __shfl(s, e);
      ex[jj] = __shfl(px, hc * 16 + e);
      ld[jj] = ((const float4*)hlin)[(size_t)sj[jj] * 32 + c];
    }
#pragma unroll
    for (int jj = 0; jj < 8; jj++) {
      acc.x += ex[jj] * ld[jj].x;
      acc.y += ex[jj] * ld[jj].y;
      acc.z += ex[jj] * ld[jj].z;
      acc.w += ex[jj] * ld[jj].w;
      dh += ex[jj];
    }
  }

  // combine even/odd halves (lane ^ 32 holds the complementary partial)
  acc.x += __shfl_xor(acc.x, 32);
  acc.y += __shfl_xor(acc.y, 32);
  acc.z += __shfl_xor(acc.z, 32);
  acc.w += __shfl_xor(acc.w, 32);
  dh += __shfl_xor(dh, 32);

  float inv = 1.f / (dh + GEPS);
  float4 bv = ((const float4*)bias)[c];
  if (p == 0) {
    float4 o;
    o.x = fmaxf(acc.x * inv + bv.x, 0.f);
    o.y = fmaxf(acc.y * inv + bv.y, 0.f);
    o.z = fmaxf(acc.z * inv + bv.z, 0.f);
    o.w = fmaxf(acc.w * inv + bv.w, 0.f);
    ((float4*)hout)[(size_t)n * 32 + c] = o;
  }
}

// ---------------- global attention pooling ----------------
__global__ __launch_bounds__(256) void k_pool(const float* __restrict__ h,
                                              const float* __restrict__ gate_w,
                                              const float* __restrict__ gate_b,
                                              float* __restrict__ acc_out) {
  const int lane = threadIdx.x & 63;
  const int widg = blockIdx.x * 4 + (threadIdx.x >> 6);
  const int nw = gridDim.x * 4;
  const float w0 = gate_w[lane * 2], w1 = gate_w[lane * 2 + 1];
  const float gb = gate_b[0];
  float acc0 = 0.f, acc1 = 0.f, se = 0.f;
  for (int n = widg; n < NN; n += nw) {
    float2 hv = ((const float2*)h)[(size_t)n * 64 + lane];
    float p = hv.x * w0 + hv.y * w1;
#pragma unroll
    for (int off = 1; off < 64; off <<= 1) p += __shfl_xor(p, off);
    float sg = 1.f / (1.f + __expf(-(p + gb)));
    float e = __expf(sg);
    se += e;
    acc0 += e * hv.x;
    acc1 += e * hv.y;
  }
  atomicAdd(&acc_out[lane * 2], acc0);
  atomicAdd(&acc_out[lane * 2 + 1], acc1);
  if (lane == 0) atomicAdd(&acc_out[128], se);
}

// ---------------- final MLP ----------------
__global__ __launch_bounds__(128) void k_mlp(const float* __restrict__ p1,
                                             const float* __restrict__ p2,
                                             const float* __restrict__ fc1_w,
                                             const float* __restrict__ fc1_b,
                                             const float* __restrict__ fc2_w,
                                             const float* __restrict__ fc2_b,
                                             float* __restrict__ out) {
  __shared__ float cat[256];
  __shared__ float red[2];
  const int t = threadIdx.x;
  cat[t] = p1[t] / p1[128];
  cat[128 + t] = p2[t] / p2[128];
  __syncthreads();
  float a = fc1_b[t];
  for (int k = 0; k < 256; k++) a += cat[k] * fc1_w[k * 128 + t];
  a = fmaxf(a, 0.f);
  float v = a * fc2_w[t];
#pragma unroll
  for (int off = 1; off < 64; off <<= 1) v += __shfl_xor(v, off);
  if ((t & 63) == 0) red[t >> 6] = v;
  __syncthreads();
  if (t == 0) out[0] = red[0] + red[1] + fc2_b[0];
}

extern "C" void kernel_launch(void* const* d_in, const int* in_sizes, int n_in,
                              void* d_out, int out_size, void* d_ws, size_t ws_size,
                              hipStream_t stream) {
  (void)in_sizes; (void)n_in; (void)out_size;
  const int* x1 = (const int*)d_in[0];
  const int* x2 = (const int*)d_in[1];
  const int* ei1 = (const int*)d_in[2];
  const int* ei2 = (const int*)d_in[3];
  const float* embed = (const float*)d_in[4];
  const float* W = (const float*)d_in[5];
  const float* attS = (const float*)d_in[6];
  const float* attD = (const float*)d_in[7];
  const float* bias = (const float*)d_in[8];
  const float* gw = (const float*)d_in[9];
  const float* gb = (const float*)d_in[10];
  const float* f1w = (const float*)d_in[11];
  const float* f1b = (const float*)d_in[12];
  const float* f2w = (const float*)d_in[13];
  const float* f2b = (const float*)d_in[14];
  float* out = (float*)d_out;

  auto req = [](int nt, int net) {
    size_t s = 0;
    auto pad = [&](size_t b) { s = (s + b + 255) & ~size_t(255); };
    pad(size_t(nt) * DIM * 4);
    pad(size_t(nt) * DIM * 4);
    pad(size_t(nt) * 16);
    pad(size_t(nt) * 16);
    pad(size_t(nt + 1) * 4);
    pad(size_t(nt) * 4);
    pad(size_t(net) * 4);
    pad(128 * 4);
    pad(2 * 129 * 4);
    return s;
  };
  const bool combined = ws_size >= req(2 * NN, 2 * NE);
  const int nt = combined ? 2 * NN : NN;
  const int net = combined ? 2 * NE : NE;

  char* ws = (char*)d_ws;
  size_t off = 0;
  auto alloc = [&](size_t bytes) {
    void* p = ws + off;
    off = (off + bytes + 255) & ~size_t(255);
    return p;
  };
  float* h_in = (float*)alloc(size_t(nt) * DIM * 4);
  float* h_lin = (float*)alloc(size_t(nt) * DIM * 4);
  float* asrc = (float*)alloc(size_t(nt) * 16);
  float* adst = (float*)alloc(size_t(nt) * 16);
  int* roff = (int*)alloc(size_t(nt + 1) * 4);
  int* cur = (int*)alloc(size_t(nt) * 4);
  int* ssrc = (int*)alloc(size_t(net) * 4);
  int* partials = (int*)alloc(128 * 4);
  float* pool = (float*)alloc(2 * 129 * 4);

  hipMemsetAsync(pool, 0, 2 * 129 * 4, stream);

  const int nb = (nt + 1023) / 1024;
  const int lgrid = (nt + 63) / 64;

  auto run_graphs = [&](const int* xA, const int* xB, const int* eA, const int* eB) {
    hipMemsetAsync(cur, 0, size_t(nt) * 4, stream);
    k_count<<<(net + 255) / 256, 256, 0, stream>>>(eA + NE, eB + NE, cur, net);
    k_scan1<<<nb, 1024, 0, stream>>>(cur, roff, partials, nt);
    k_scan2<<<1, 128, 0, stream>>>(partials, nb);
    k_scan3<<<nb, 1024, 0, stream>>>(roff, cur, partials, nt, net);
    k_fill<<<(net + 255) / 256, 256, 0, stream>>>(eA, eA + NE, eB, eB + NE, cur, ssrc, net);
    for (int l = 0; l < 3; ++l) {
      if (l == 0) {
        k_linear<<<lgrid, 256, 0, stream>>>(
            embed, xA, xB, W, attS, attD, h_lin, asrc, adst, nt);
      } else {
        k_linear<<<lgrid, 256, 0, stream>>>(
            h_in, nullptr, nullptr, W + l * DIM * DIM, attS + l * DIM, attD + l * DIM,
            h_lin, asrc, adst, nt);
      }
      k_aggregate<<<(nt + 3) / 4, 256, 0, stream>>>(
          h_lin, asrc, adst, roff, ssrc, bias + l * DIM, h_in, nt);
    }
  };

  if (combined) {
    run_graphs(x1, x2, ei1, ei2);
    k_pool<<<128, 256, 0, stream>>>(h_in, gw, gb, pool);
    k_pool<<<128, 256, 0, stream>>>(h_in + size_t(NN) * DIM, gw, gb, pool + 129);
  } else {
    run_graphs(x1, x1, ei1, ei1);
    k_pool<<<128, 256, 0, stream>>>(h_in, gw, gb, pool);
    run_graphs(x2, x2, ei2, ei2);
    k_pool<<<128, 256, 0, stream>>>(h_in, gw, gb, pool + 129);
  }
  k_mlp<<<1, 128, 0, stream>>>(pool, pool + 129, f1w, f1b, f2w, f2b, out);
}